// Round 10
// baseline (108.517 us; speedup 1.0000x reference)
//
#include <hip/hip_runtime.h>

typedef float  f32x4 __attribute__((ext_vector_type(4)));
typedef float  f32x2 __attribute__((ext_vector_type(2)));
typedef short  short8v __attribute__((ext_vector_type(8)));

static __device__ __forceinline__ unsigned short f2bf(float f) {
  union { float f; unsigned u; } v; v.f = f;
  unsigned r = v.u + 0x7FFFu + ((v.u >> 16) & 1u);   // RNE
  return (unsigned short)(r >> 16);
}
static __device__ __forceinline__ float bf2f(unsigned short h) {
  union { unsigned u; float f; } v; v.u = ((unsigned)h) << 16;
  return v.f;
}
static __device__ __forceinline__ f32x4 mfma16(short8v a, short8v b, f32x4 c) {
  return __builtin_amdgcn_mfma_f32_16x16x32_bf16(a, b, c, 0, 0, 0);
}

// Fragment-packed layout: element (r,c) of an [R][C] bf16 MFMA operand lives at
// pack[((r>>4)*(C>>5) + (c>>5))*512 + (((c>>3)&3)*16 + (r&15))*8 + (c&7)].
static __device__ __forceinline__ size_t pidx(int r, int c, int C) {
  return (((size_t)(r >> 4) * (C >> 5) + (c >> 5)) << 9) +
         ((size_t)((((c >> 3) & 3) << 4) + (r & 15)) << 3) + (c & 7);
}

static __device__ __forceinline__ float elt(const float* r, int c) { return r[c]; }
static __device__ __forceinline__ float elt(const unsigned short* r, int c) { return bf2f(r[c]); }

// ---- load NF consecutive floats (no wrap) ----
template <int NF>
static __device__ __forceinline__ void load_f(const float* row, int c0, float* f) {
  #pragma unroll
  for (int u = 0; u < (NF - 2) / 4; ++u)
    *(f32x4*)(f + 4 * u) = *(const f32x4*)(row + c0 + 4 * u);
  *(f32x2*)(f + NF - 2) = *(const f32x2*)(row + c0 + NF - 2);
}
template <int NF>
static __device__ __forceinline__ void load_f(const unsigned short* row, int c0, float* f) {
  #pragma unroll
  for (int u = 0; u < NF / 2; ++u) {
    unsigned a = *(const unsigned*)(row + c0 + 2 * u);
    f[2 * u]     = bf2f((unsigned short)a);
    f[2 * u + 1] = bf2f((unsigned short)(a >> 16));
  }
}

// ---- adj pooling body: out[j,k] = 4x4 window sum (bf16 row-major + packed)
// + f32 rowsum + diag. One output row per call; thread owns KCNT consecutive k.
template <typename T, int KCNT>
static __device__ void pool_adj_body(const T* __restrict__ in,
                                     unsigned short* __restrict__ outh,   // row-major (may be null)
                                     unsigned short* __restrict__ outp,   // packed
                                     float* __restrict__ rs,
                                     float* __restrict__ diag,
                                     int n, int nin, int bid, float* red) {
  constexpr int NF = 2 * KCNT + 2;
  int chunk = n >> 3;                       // n % 8 == 0 -> bijective swizzle
  int j = (bid & 7) * chunk + (bid >> 3);
  int r0 = 2 * j;
  const T* row0 = in + (size_t)((r0 + 0) & (nin - 1)) * nin;
  const T* row1 = in + (size_t)((r0 + 1) & (nin - 1)) * nin;
  const T* row2 = in + (size_t)((r0 + 2) & (nin - 1)) * nin;
  const T* row3 = in + (size_t)((r0 + 3) & (nin - 1)) * nin;
  int t = threadIdx.x;
  int k0 = t * KCNT;
  int c0 = 2 * k0;
  float F[NF];
  if (c0 + NF <= nin) {
    float f[NF];
    load_f<NF>(row0, c0, F);
    load_f<NF>(row1, c0, f);
    #pragma unroll
    for (int u = 0; u < NF; ++u) F[u] += f[u];
    load_f<NF>(row2, c0, f);
    #pragma unroll
    for (int u = 0; u < NF; ++u) F[u] += f[u];
    load_f<NF>(row3, c0, f);
    #pragma unroll
    for (int u = 0; u < NF; ++u) F[u] += f[u];
  } else {
    #pragma unroll
    for (int u = 0; u < NF; ++u) {
      int c = (c0 + u) & (nin - 1);
      F[u] = elt(row0, c) + elt(row1, c) + elt(row2, c) + elt(row3, c);
    }
  }
  float pr[KCNT + 1];
  #pragma unroll
  for (int m = 0; m <= KCNT; ++m) pr[m] = F[2 * m] + F[2 * m + 1];
  float racc = 0.f;
  unsigned short hv[KCNT];
  #pragma unroll
  for (int kl = 0; kl < KCNT; ++kl) {
    float s = pr[kl] + pr[kl + 1];
    hv[kl] = f2bf(s);
    racc += s;
    if (k0 + kl == j) diag[j] = s;
  }
  if constexpr (KCNT == 8) {
    short8v o8;
    #pragma unroll
    for (int kl = 0; kl < 8; ++kl) o8[kl] = (short)hv[kl];
    if (outh) *(short8v*)&outh[(size_t)j * n + k0] = o8;
    *(short8v*)&outp[pidx(j, k0, n)] = o8;
  } else {
    uint2 o4;
    o4.x = (unsigned)hv[0] | ((unsigned)hv[1] << 16);
    o4.y = (unsigned)hv[2] | ((unsigned)hv[3] << 16);
    if (outh) *(uint2*)&outh[(size_t)j * n + k0] = o4;
    *(uint2*)&outp[pidx(j, k0, n)] = o4;
  }
  #pragma unroll
  for (int o = 32; o > 0; o >>= 1) racc += __shfl_xor(racc, o);
  if ((threadIdx.x & 63) == 0) red[threadIdx.x >> 6] = racc;
  __syncthreads();
  if (threadIdx.x == 0) rs[j] = red[0] + red[1] + red[2] + red[3];
}

// ---- K hi/lo + V packed from x (flat, 4 elements/thread)
static __device__ void split_body(const float* __restrict__ X,
                                  unsigned short* __restrict__ Kph,
                                  unsigned short* __restrict__ Kpl,
                                  unsigned short* __restrict__ Vp,
                                  int bb) {
  #pragma unroll
  for (int r = 0; r < 4; ++r) {
    int e = bb * 1024 + r * 256 + threadIdx.x;
    int i = e >> 7, d = e & 127;
    float v = X[e];
    unsigned short hi = f2bf(v);
    Kph[pidx(i, d, 128)] = hi;                    // K consumed r=node, c=feature
    Kpl[pidx(i, d, 128)] = f2bf(v - bf2f(hi));
    Vp[pidx(d, i, 4096)] = hi;                    // V consumed r=feature, c=node
  }
}

// ---- 16x128 @ 128x128 gemm body (xs in LDS, thread owns col d)
static __device__ __forceinline__ void gemm16x128(const float (*xs)[128],
                                                  const float* __restrict__ W,
                                                  int d, float* acc) {
  #pragma unroll
  for (int i = 0; i < 16; ++i) acc[i] = 0.f;
  for (int e = 0; e < 128; e += 4) {
    float w0 = W[(e + 0) * 128 + d];
    float w1 = W[(e + 1) * 128 + d];
    float w2 = W[(e + 2) * 128 + d];
    float w3 = W[(e + 3) * 128 + d];
    #pragma unroll
    for (int i = 0; i < 16; ++i) {
      f32x4 xv = *(const f32x4*)&xs[i][e];
      float a = acc[i];
      a = fmaf(xv[0], w0, a);
      a = fmaf(xv[1], w1, a);
      a = fmaf(xv[2], w2, a);
      a = fmaf(xv[3], w3, a);
      acc[i] = a;
    }
  }
}

// ---- 8-row variant: rows ibase..ibase+7 of xs
static __device__ __forceinline__ void gemm8x128(const float (*xs)[128], int ibase,
                                                 const float* __restrict__ W,
                                                 int d, float* acc) {
  #pragma unroll
  for (int i = 0; i < 8; ++i) acc[i] = 0.f;
  for (int e = 0; e < 128; e += 4) {
    float w0 = W[(e + 0) * 128 + d];
    float w1 = W[(e + 1) * 128 + d];
    float w2 = W[(e + 2) * 128 + d];
    float w3 = W[(e + 3) * 128 + d];
    #pragma unroll
    for (int i = 0; i < 8; ++i) {
      f32x4 xv = *(const f32x4*)&xs[ibase + i][e];
      float a = acc[i];
      a = fmaf(xv[0], w0, a);
      a = fmaf(xv[1], w1, a);
      a = fmaf(xv[2], w2, a);
      a = fmaf(xv[3], w3, a);
      acc[i] = a;
    }
  }
}

// ---- x1b = row-pool(x); Q = x1b @ ca1 -> packed hi/lo. 128 threads per tile.
static __device__ void gemm_q_body(const float* __restrict__ x,
                                   const float* __restrict__ W,
                                   float* __restrict__ x1b,
                                   unsigned short* __restrict__ Qph,
                                   unsigned short* __restrict__ Qpl,
                                   int tile, float (*xs)[128], int d) {
  int r0 = tile * 16;
  #pragma unroll
  for (int i = 0; i < 16; ++i) {
    int rr = 2 * (r0 + i);
    float v = x[(size_t)((rr + 0) & 4095) * 128 + d] + x[(size_t)((rr + 1) & 4095) * 128 + d] +
              x[(size_t)((rr + 2) & 4095) * 128 + d] + x[(size_t)((rr + 3) & 4095) * 128 + d];
    xs[i][d] = v;
    x1b[(size_t)(r0 + i) * 128 + d] = v;
  }
  __syncthreads();
  float acc[16];
  gemm16x128(xs, W, d, acc);
  #pragma unroll
  for (int i = 0; i < 16; ++i) {
    size_t o = pidx(r0 + i, d, 128);              // Q consumed r=node, c=feature
    unsigned short hi = f2bf(acc[i]);
    Qph[o] = hi;
    Qpl[o] = f2bf(acc[i] - bf2f(hi));
  }
}

// ---- prep: K/V packed split || x1b + Q packed gemm (everything flash needs)
__global__ __launch_bounds__(256) void prep_kernel(const float* __restrict__ x,
                                                   unsigned short* __restrict__ Kph,
                                                   unsigned short* __restrict__ Kpl,
                                                   unsigned short* __restrict__ Vp,
                                                   const float* __restrict__ ca1,
                                                   float* __restrict__ x1b,
                                                   unsigned short* __restrict__ Qph,
                                                   unsigned short* __restrict__ Qpl) {
  __shared__ __align__(16) char smem[16384];
  int b = blockIdx.x;
  if (b < 512) {
    split_body(x, Kph, Kpl, Vp, b);
  } else {
    int half = threadIdx.x >> 7, d = threadIdx.x & 127;
    float (*xs)[128] = (float (*)[128])(smem + half * 8192);
    gemm_q_body(x, ca1, x1b, Qph, Qpl, (b - 512) * 2 + half, xs, d);
  }
}

// ---- split-K flash attention body (bf16x3 QK^T, masked-to-zero scores).
// One wave: q-rows jt*16..+15 over k-range kc*256..+255; 4 lockstep waves of a
// block share the same kc -> identical K/V fragment loads hit L1.
static __device__ void flash_body(const short8v* __restrict__ Qh8,
                                  const short8v* __restrict__ Ql8,
                                  const short8v* __restrict__ Kh8,
                                  const short8v* __restrict__ Kl8,
                                  const short8v* __restrict__ V8,
                                  uint2* __restrict__ pacc2,
                                  float* __restrict__ pm,
                                  float* __restrict__ pl,
                                  int jt, int kc, int lane,
                                  unsigned short (*P)[32]) {
  int q = lane & 15, g = lane >> 4;
  int j = jt * 16 + q;
  int kbase = kc * 256;
  int twoj = 2 * j;

  short8v qh[4], ql[4];
  #pragma unroll
  for (int c = 0; c < 4; ++c) {
    qh[c] = Qh8[(size_t)(jt * 4 + c) * 64 + lane];
    ql[c] = Ql8[(size_t)(jt * 4 + c) * 64 + lane];
  }
  float m = -1e30f, l = 0.f;
  f32x4 acc[8];
  #pragma unroll
  for (int t = 0; t < 8; ++t) acc[t] = (f32x4){0.f, 0.f, 0.f, 0.f};

  for (int step = 0; step < 8; ++step) {
    int kt = kbase + step * 32;
    size_t fa = (size_t)(kt >> 4) * 4;        // rowblock a (even), b = a+1
    f32x4 z = {0.f, 0.f, 0.f, 0.f};
    f32x4 hh0 = z, hl0 = z, lh0 = z, hh1 = z, hl1 = z, lh1 = z;
    __builtin_amdgcn_s_setprio(1);
    #pragma unroll
    for (int c = 0; c < 4; ++c) {
      short8v ah = Kh8[(fa + c) * 64 + lane];
      short8v al = Kl8[(fa + c) * 64 + lane];
      short8v bh = Kh8[(fa + 4 + c) * 64 + lane];
      short8v bl = Kl8[(fa + 4 + c) * 64 + lane];
      hh0 = mfma16(ah, qh[c], hh0);   // 6 independent 4-deep chains
      hh1 = mfma16(bh, qh[c], hh1);
      hl0 = mfma16(ah, ql[c], hl0);
      hl1 = mfma16(bh, ql[c], hl1);
      lh0 = mfma16(al, qh[c], lh0);
      lh1 = mfma16(bl, qh[c], lh1);
    }
    __builtin_amdgcn_s_setprio(0);
    // prefetch V fragments (contiguous packed): consumed after softmax
    short8v vfrag[8];
    #pragma unroll
    for (int t = 0; t < 8; ++t)
      vfrag[t] = V8[((size_t)t * 128 + (kt >> 5)) * 64 + lane];

    f32x4 s0 = hh0 + hl0 + lh0;
    f32x4 s1 = hh1 + hl1 + lh1;
    float sv[8];
    #pragma unroll
    for (int r = 0; r < 4; ++r) {
      int k0 = kt + g * 4 + r;          // D row = k-within-tile = 4g+r
      float v0 = s0[r];
      if (((k0 - twoj) & 4095) < 4) v0 = 0.f;
      sv[r] = v0;
      int k1 = k0 + 16;
      float v1 = s1[r];
      if (((k1 - twoj) & 4095) < 4) v1 = 0.f;
      sv[4 + r] = v1;
    }
    float cmx = sv[0];
    #pragma unroll
    for (int r = 1; r < 8; ++r) cmx = fmaxf(cmx, sv[r]);
    cmx = fmaxf(cmx, __shfl_xor(cmx, 16));
    cmx = fmaxf(cmx, __shfl_xor(cmx, 32));
    float mnew = fmaxf(m, cmx);
    float ps = 0.f;
    unsigned short pb[8];
    #pragma unroll
    for (int r = 0; r < 8; ++r) {
      float pv = __expf(sv[r] - mnew);
      ps += pv;
      pb[r] = f2bf(pv);
    }
    ps += __shfl_xor(ps, 16);
    ps += __shfl_xor(ps, 32);
    if (__any(cmx > m)) {               // defer-rescale: skip when max didn't grow
      float scl = __expf(m - mnew);
      l *= scl;
      float sc0 = __shfl(scl, 4 * g + 0);
      float sc1 = __shfl(scl, 4 * g + 1);
      float sc2 = __shfl(scl, 4 * g + 2);
      float sc3 = __shfl(scl, 4 * g + 3);
      #pragma unroll
      for (int t = 0; t < 8; ++t) {
        acc[t][0] *= sc0; acc[t][1] *= sc1; acc[t][2] *= sc2; acc[t][3] *= sc3;
      }
    }
    m = mnew;
    l += ps;
    // write P[q][k_local]: tile a k_local=4g+r, tile b 16+4g+r (packed pairs)
    *(unsigned*)&P[q][4 * g]          = (unsigned)pb[0] | ((unsigned)pb[1] << 16);
    *(unsigned*)&P[q][4 * g + 2]      = (unsigned)pb[2] | ((unsigned)pb[3] << 16);
    *(unsigned*)&P[q][16 + 4 * g]     = (unsigned)pb[4] | ((unsigned)pb[5] << 16);
    *(unsigned*)&P[q][16 + 4 * g + 2] = (unsigned)pb[6] | ((unsigned)pb[7] << 16);
    __syncthreads();
    short8v pa = *(const short8v*)&P[q][8 * g];   // A-frag: row q, k=8g+e
    __builtin_amdgcn_s_setprio(1);
    #pragma unroll
    for (int t = 0; t < 8; ++t) acc[t] = mfma16(pa, vfrag[t], acc[t]);
    __builtin_amdgcn_s_setprio(0);
    __syncthreads();
  }
  size_t tau = (size_t)jt * 16 + kc;
  #pragma unroll
  for (int t = 0; t < 8; ++t) {
    uint2 o;
    o.x = (unsigned)f2bf(acc[t][0]) | ((unsigned)f2bf(acc[t][1]) << 16);
    o.y = (unsigned)f2bf(acc[t][2]) | ((unsigned)f2bf(acc[t][3]) << 16);
    pacc2[(tau * 8 + t) * 64 + lane] = o;
  }
  if (g == 0) {
    pm[(size_t)j * 16 + kc] = m;
    pl[(size_t)j * 16 + kc] = l;
  }
}

// ---- megaB: flash (blocks 0-511, compute) || pool_adj1 (blocks 512+, HBM-bound)
__global__ __launch_bounds__(256) void megaB_kernel(const float* __restrict__ newadj,
                                                    unsigned short* __restrict__ adj1h,
                                                    unsigned short* __restrict__ adj1p,
                                                    float* __restrict__ rs1,
                                                    float* __restrict__ diag1,
                                                    const short8v* __restrict__ Qh8,
                                                    const short8v* __restrict__ Ql8,
                                                    const short8v* __restrict__ Kh8,
                                                    const short8v* __restrict__ Kl8,
                                                    const short8v* __restrict__ V8,
                                                    uint2* __restrict__ pacc2,
                                                    float* __restrict__ pm,
                                                    float* __restrict__ pl) {
  __shared__ __align__(16) char smem[4096];
  int b = blockIdx.x;
  if (b < 512) {
    int w = threadIdx.x >> 6, lane = threadIdx.x & 63;
    int kc = b & 15;
    int jt = (b >> 4) * 4 + w;
    unsigned short (*P)[32] = (unsigned short (*)[32])(smem + w * 1024);
    flash_body(Qh8, Ql8, Kh8, Kl8, V8, pacc2, pm, pl, jt, kc, lane, P);
  } else {
    pool_adj_body<float, 8>(newadj, adj1h, adj1p, rs1, diag1, 2048, 4096, b - 512, (float*)smem);
  }
}

// ---- merge split-K partials (LDS-staged, coalesced) -> x1; y = d1.*(x1@W1); packed yT
// One jt (16 rows) per block; its ENTIRE pacc input is 64KB contiguous.
__global__ __launch_bounds__(256) void combine_gemm_kernel(const uint4* __restrict__ pacc4,
                                                           const float* __restrict__ pm,
                                                           const float* __restrict__ pl,
                                                           const float* __restrict__ x1b,
                                                           const float* __restrict__ W,
                                                           const float* __restrict__ rs,
                                                           const float* __restrict__ diag,
                                                           float* __restrict__ yB,
                                                           unsigned short* __restrict__ ypack,
                                                           int M) {
  __shared__ unsigned short pL[32768];      // 64 KB: [kc*2048 + t*256 + (g*16+q)*4 + r]
  __shared__ float pmL[256], plL[256];
  __shared__ float xs[16][128];
  int jt = blockIdx.x;
  int r0 = jt * 16;
  int tid = threadIdx.x;
  const uint4* src = pacc4 + (size_t)jt * 4096;   // 16kc*8t*64lane uint2 = 4096 uint4
  uint4* dst = (uint4*)pL;
  #pragma unroll
  for (int u = 0; u < 16; ++u) dst[u * 256 + tid] = src[u * 256 + tid];
  pmL[tid] = pm[(size_t)r0 * 16 + tid];
  plL[tid] = pl[(size_t)r0 * 16 + tid];
  __syncthreads();
  int h = tid >> 7, d = tid & 127;
  int t = d >> 4, q = d & 15;
  #pragma unroll
  for (int ii = 0; ii < 8; ++ii) {
    int i = h * 8 + ii;
    int j = r0 + i;
    int g = i >> 2, r = i & 3;
    int off = t * 256 + (g * 16 + q) * 4 + r;
    float Mx = -1e30f;
    #pragma unroll
    for (int c = 0; c < 16; ++c) Mx = fmaxf(Mx, pmL[i * 16 + c]);
    float L = 0.f, o = 0.f;
    #pragma unroll
    for (int c = 0; c < 16; ++c) {
      float w = __expf(pmL[i * 16 + c] - Mx);
      L += plL[i * 16 + c] * w;
      o += w * bf2f(pL[c * 2048 + off]);
    }
    xs[i][d] = o / L + x1b[(size_t)j * 128 + d];
  }
  __syncthreads();
  float acc[8];
  gemm8x128(xs, h * 8, W, d, acc);
  short8v t0;
  #pragma unroll
  for (int ii = 0; ii < 8; ++ii) {
    int j = r0 + h * 8 + ii;
    float dv = rsqrtf(fmaxf(rs[j] - diag[j] + 1.f, 1.f));
    float v = acc[ii] * dv;
    yB[(size_t)j * 128 + d] = v;
    t0[ii] = (short)f2bf(v);
  }
  // y consumed as B-operand: r = feature d, c = node j
  *(short8v*)&ypack[pidx(d, r0 + h * 8, M)] = t0;
}

// ---- one-wave MFMA tile on packed operands: C_ks partial = A @ B
static __device__ void mfma_tile_body(const short8v* __restrict__ A8,
                                      const short8v* __restrict__ B8,
                                      float* __restrict__ C, int K32, int M,
                                      int jt, int nt, int ks, int lane) {
  int q = lane & 15, g = lane >> 4;
  int half = K32 >> 1;
  const short8v* ap = A8 + ((size_t)jt * K32 + ks * half) * 64 + lane;
  const short8v* bp = B8 + ((size_t)nt * K32 + ks * half) * 64 + lane;
  f32x4 acc = {0.f, 0.f, 0.f, 0.f};
  for (int kc = 0; kc < half; kc += 4) {
    #pragma unroll
    for (int u = 0; u < 4; ++u)
      acc = mfma16(ap[(size_t)(kc + u) * 64], bp[(size_t)(kc + u) * 64], acc);
  }
  float* Cp = C + (size_t)ks * M * 128;
  #pragma unroll
  for (int r = 0; r < 4; ++r)
    Cp[(size_t)(jt * 16 + g * 4 + r) * 128 + nt * 16 + q] = acc[r];
}

// ---- mega2: mfma_gemm(level1, 4 waves/block) || pool_adj(level2, packed-only)
//      Block 0 also zeroes the completion counter for epi_final.
__global__ __launch_bounds__(256) void mega2_kernel(const unsigned short* __restrict__ adj1h,
                                                    const short8v* __restrict__ adj1p8,
                                                    const short8v* __restrict__ yp8,
                                                    float* __restrict__ G,
                                                    unsigned short* __restrict__ adj2p,
                                                    float* __restrict__ rs2,
                                                    float* __restrict__ diag2,
                                                    unsigned* __restrict__ cnt) {
  __shared__ float red[4];
  int b = blockIdx.x;
  if (b == 0 && threadIdx.x == 0) *cnt = 0;
  if (b < 512) {
    int fid = b * 4 + (threadIdx.x >> 6);       // [0,2048)
    int jt = fid & 127, nt = (fid >> 7) & 7, ks = fid >> 10;
    mfma_tile_body(adj1p8, yp8, G, 64, 2048, jt, nt, ks, threadIdx.x & 63);
  } else {
    pool_adj_body<unsigned short, 4>(adj1h, nullptr, adj2p, rs2, diag2, 1024, 2048, b - 512, red);
  }
}

// ---- GCN epilogue element: h[r][d] (G = 2 K-split partials, n rows each)
static __device__ __forceinline__ float epi_h(const float* __restrict__ G,
                                              const float* __restrict__ y,
                                              const float* __restrict__ rs,
                                              const float* __restrict__ diag,
                                              const float* __restrict__ bias,
                                              int n, int r, int d, bool relu) {
  float dv = rsqrtf(fmaxf(rs[r] - diag[r] + 1.f, 1.f));
  float gs = G[(size_t)r * 128 + d] + G[(size_t)(n + r) * 128 + d];
  float v = dv * (gs + (1.f - diag[r]) * y[(size_t)r * 128 + d]) + bias[d];
  return relu ? fmaxf(v, 0.f) : v;
}

// ---- epi_final: level-2 collapsed algebraically.
// colsum(h2, real rows, no bias) = sum_k u[k]*y2[k,:], u[k] = w[k] + d2[k](1-diag2[k]),
// w[k] = sum_j d2[j]*adj2[j,k]. Block b owns k-range [8b..8b+7]: it computes
// w (64 contiguous 256B chunks of packed adj2), its y2 rows IN REGISTERS
// (x2 = pool(relu-gcn1); y2 = d2.*(x2@W2)), the u-weighted partial, and the
// gated last block finishes mean + linear + relu + log_softmax.
__global__ __launch_bounds__(128) void epi_final_kernel(const float* __restrict__ G,
                                                        const float* __restrict__ yB,
                                                        const float* __restrict__ rs1,
                                                        const float* __restrict__ diag1,
                                                        const float* __restrict__ b1,
                                                        const float* __restrict__ W,
                                                        const float* __restrict__ rs2,
                                                        const float* __restrict__ diag2,
                                                        const float* __restrict__ b2,
                                                        const unsigned short* __restrict__ adj2p,
                                                        float* __restrict__ part,
                                                        unsigned* __restrict__ cnt,
                                                        const float* __restrict__ Wlin,
                                                        const float* __restrict__ blin,
                                                        float* __restrict__ out,
                                                        int n1) {
  __shared__ float xs[8][128];
  __shared__ float wred[16][8];
  __shared__ float uval[8];
  __shared__ float rr0[128], rr1[128];
  __shared__ unsigned doneS;
  int b = blockIdx.x;            // 0..127, k-range = rows r0..r0+7
  int tid = threadIdx.x;
  int r0 = b * 8;
  // ---- w[r0+u] = sum_r d2[r] * adj2[r, r0+u]; packed chunk walk, coalesced
  {
    const unsigned short* base = adj2p + (size_t)(b >> 2) * 512 + (size_t)(b & 3) * 128 + tid;
    int s = tid >> 3;                           // r within 16-row group
    float wacc = 0.f;
    for (int mm = 0; mm < 64; ++mm) {
      int r = mm * 16 + s;
      float d2r = rsqrtf(fmaxf(rs2[r] - diag2[r] + 1.f, 1.f));
      wacc += d2r * bf2f(base[(size_t)mm * 16384]);
    }
    wred[s][tid & 7] = wacc;
  }
  __syncthreads();
  if (tid < 8) {
    float wsum = 0.f;
    #pragma unroll
    for (int s2 = 0; s2 < 16; ++s2) wsum += wred[s2][tid];
    int k = r0 + tid;
    float d2k = rsqrtf(fmaxf(rs2[k] - diag2[k] + 1.f, 1.f));
    uval[tid] = wsum + d2k * (1.f - diag2[k]);
  }
  // ---- x2 rows r0..r0+7 (pool of relu-gcn1), y2 in registers, u-weighted partial
  int d = tid;
  #pragma unroll
  for (int i = 0; i < 8; ++i) {
    int rr = 2 * (r0 + i);
    float s = 0.f;
    #pragma unroll
    for (int a = 0; a < 4; ++a)
      s += epi_h(G, yB, rs1, diag1, b1, n1, (rr + a) & (n1 - 1), d, true);
    xs[i][d] = s;
  }
  __syncthreads();                              // also publishes uval
  float acc[8];
  gemm8x128(xs, 0, W, d, acc);
  float pd = 0.f;
  #pragma unroll
  for (int i = 0; i < 8; ++i) {
    int j = r0 + i;
    float dv = rsqrtf(fmaxf(rs2[j] - diag2[j] + 1.f, 1.f));
    pd += uval[i] * (acc[i] * dv);
  }
  part[(size_t)b * 128 + d] = pd;
  __threadfence();
  __syncthreads();
  if (tid == 0) doneS = atomicAdd(cnt, 1u);
  __syncthreads();
  if (doneS == 127) {                           // last block: all partials visible
    __threadfence();
    float cs = 0.f;
    for (int bb = 0; bb < 128; ++bb) cs += part[(size_t)bb * 128 + d];
    // + 1024*b2 (real rows' bias) + 1024*b2 (phantom rows) -> /2048 = + b2
    float mean = cs * (1.f / 2048.f) + b2[d];
    rr0[d] = mean * Wlin[d];
    rr1[d] = mean * Wlin[128 + d];
    __syncthreads();
    for (int sred = 64; sred > 0; sred >>= 1) {
      if (tid < sred) { rr0[tid] += rr0[tid + sred]; rr1[tid] += rr1[tid + sred]; }
      __syncthreads();
    }
    if (tid == 0) {
      float z0 = fmaxf(rr0[0] + blin[0], 0.f);
      float z1 = fmaxf(rr1[0] + blin[1], 0.f);
      float mz = fmaxf(z0, z1);
      float lse = mz + logf(__expf(z0 - mz) + __expf(z1 - mz));
      out[0] = z0 - lse;
      out[1] = z1 - lse;
    }
  }
}

extern "C" void kernel_launch(void* const* d_in, const int* in_sizes, int n_in,
                              void* d_out, int out_size, void* d_ws, size_t ws_size,
                              hipStream_t stream) {
  const float* x      = (const float*)d_in[0];
  const float* eidx   = (const float*)d_in[1];
  const float* newadj = eidx + (size_t)4096 * 4096;  // edge_index[1]
  const float* ca1    = (const float*)d_in[3];
  const float* W1     = (const float*)d_in[4];
  const float* b1     = (const float*)d_in[5];
  const float* W2     = (const float*)d_in[6];
  const float* b2     = (const float*)d_in[7];
  const float* Wlin   = (const float*)d_in[8];
  const float* blin   = (const float*)d_in[9];
  float* out = (float*)d_out;

  if (ws_size < 42u * 1024u * 1024u) return;

  char* p = (char*)d_ws;
  auto alloc = [&](size_t bytes) -> char* {
    char* r = p; p += (bytes + 255) & ~(size_t)255; return r;
  };
  unsigned short* adj1h = (unsigned short*)alloc((size_t)2048 * 2048 * 2);  // row-major (lvl2 pool input)
  unsigned short* adj1p = (unsigned short*)alloc((size_t)2048 * 2048 * 2);  // packed (MFMA A)
  float* d1raw = (float*)alloc(2048 * 4);
  float* diag1 = (float*)alloc(2048 * 4);
  float* x1b   = (float*)alloc((size_t)2048 * 128 * 4);
  unsigned short* Qph = (unsigned short*)alloc((size_t)2048 * 128 * 2);
  unsigned short* Qpl = (unsigned short*)alloc((size_t)2048 * 128 * 2);
  unsigned short* Kph = (unsigned short*)alloc((size_t)4096 * 128 * 2);
  unsigned short* Kpl = (unsigned short*)alloc((size_t)4096 * 128 * 2);
  unsigned short* Vp  = (unsigned short*)alloc((size_t)4096 * 128 * 2);
  float* pmB   = (float*)alloc((size_t)2048 * 16 * 4);
  float* plB   = (float*)alloc((size_t)2048 * 16 * 4);
  uint2* pacc2 = (uint2*)alloc((size_t)2048 * 8 * 64 * 8);
  float* yB    = (float*)alloc((size_t)2048 * 128 * 4);
  unsigned short* ypack = (unsigned short*)alloc((size_t)2048 * 128 * 2);
  float* G     = (float*)alloc((size_t)2 * 2048 * 128 * 4);
  unsigned short* adj2p = (unsigned short*)alloc((size_t)1024 * 1024 * 2);
  float* d2raw = (float*)alloc(1024 * 4);
  float* diag2 = (float*)alloc(1024 * 4);
  float* part  = (float*)alloc((size_t)128 * 128 * 4);
  unsigned* cnt = (unsigned*)alloc(256);

  // 1. K/V packed split || x1b + Q packed gemm  (everything flash needs)
  prep_kernel<<<576, 256, 0, stream>>>(x, Kph, Kpl, Vp, ca1, x1b, Qph, Qpl);
  // 2. flash attention (compute) || pool_adj1 (HBM-bound) — flash hides under pool
  megaB_kernel<<<2560, 256, 0, stream>>>(newadj, adj1h, adj1p, d1raw, diag1,
                                         (const short8v*)Qph, (const short8v*)Qpl,
                                         (const short8v*)Kph, (const short8v*)Kpl,
                                         (const short8v*)Vp, pacc2, pmB, plB);
  // 3. combine (LDS-staged coalesced) -> x1; y = d1 .* (x1 @ W1); packed yT
  combine_gemm_kernel<<<128, 256, 0, stream>>>((const uint4*)pacc2, pmB, plB,
                                               x1b, W1, d1raw, diag1, yB, ypack, 2048);
  // 4. G (2 partials) = adj1 @ y (packed) || pool_adj2 (packed); zero cnt
  mega2_kernel<<<1536, 256, 0, stream>>>(adj1h, (const short8v*)adj1p, (const short8v*)ypack,
                                         G, adj2p, d2raw, diag2, cnt);
  // 5. epi_final: w from packed adj2, y2 in registers, u-weighted colsum,
  //    gated last block -> mean + linear + relu + log_softmax
  epi_final_kernel<<<128, 128, 0, stream>>>(G, yB, d1raw, diag1, b1, W2,
                                            d2raw, diag2, b2, adj2p,
                                            part, cnt, Wlin, blin, out, 2048);
}

// Round 11
// 99.163 us; speedup vs baseline: 1.0943x; 1.0943x over previous
//
#include <hip/hip_runtime.h>

typedef float  f32x4 __attribute__((ext_vector_type(4)));
typedef float  f32x2 __attribute__((ext_vector_type(2)));
typedef short  short8v __attribute__((ext_vector_type(8)));

static __device__ __forceinline__ unsigned short f2bf(float f) {
  union { float f; unsigned u; } v; v.f = f;
  unsigned r = v.u + 0x7FFFu + ((v.u >> 16) & 1u);   // RNE
  return (unsigned short)(r >> 16);
}
static __device__ __forceinline__ float bf2f(unsigned short h) {
  union { unsigned u; float f; } v; v.u = ((unsigned)h) << 16;
  return v.f;
}
static __device__ __forceinline__ f32x4 mfma16(short8v a, short8v b, f32x4 c) {
  return __builtin_amdgcn_mfma_f32_16x16x32_bf16(a, b, c, 0, 0, 0);
}

// Fragment-packed layout: element (r,c) of an [R][C] bf16 MFMA operand lives at
// pack[((r>>4)*(C>>5) + (c>>5))*512 + (((c>>3)&3)*16 + (r&15))*8 + (c&7)].
static __device__ __forceinline__ size_t pidx(int r, int c, int C) {
  return (((size_t)(r >> 4) * (C >> 5) + (c >> 5)) << 9) +
         ((size_t)((((c >> 3) & 3) << 4) + (r & 15)) << 3) + (c & 7);
}

static __device__ __forceinline__ float elt(const float* r, int c) { return r[c]; }
static __device__ __forceinline__ float elt(const unsigned short* r, int c) { return bf2f(r[c]); }

// ---- load NF consecutive floats (no wrap) ----
template <int NF>
static __device__ __forceinline__ void load_f(const float* row, int c0, float* f) {
  #pragma unroll
  for (int u = 0; u < (NF - 2) / 4; ++u)
    *(f32x4*)(f + 4 * u) = *(const f32x4*)(row + c0 + 4 * u);
  *(f32x2*)(f + NF - 2) = *(const f32x2*)(row + c0 + NF - 2);
}
template <int NF>
static __device__ __forceinline__ void load_f(const unsigned short* row, int c0, float* f) {
  #pragma unroll
  for (int u = 0; u < NF / 2; ++u) {
    unsigned a = *(const unsigned*)(row + c0 + 2 * u);
    f[2 * u]     = bf2f((unsigned short)a);
    f[2 * u + 1] = bf2f((unsigned short)(a >> 16));
  }
}

// ---- adj pooling body: out[j,k] = 4x4 window sum (bf16 row-major + packed)
// + f32 rowsum + diag. One output row per call; thread owns KCNT consecutive k.
template <typename T, int KCNT>
static __device__ void pool_adj_body(const T* __restrict__ in,
                                     unsigned short* __restrict__ outh,   // row-major (may be null)
                                     unsigned short* __restrict__ outp,   // packed
                                     float* __restrict__ rs,
                                     float* __restrict__ diag,
                                     int n, int nin, int bid, float* red) {
  constexpr int NF = 2 * KCNT + 2;
  int chunk = n >> 3;                       // n % 8 == 0 -> bijective swizzle
  int j = (bid & 7) * chunk + (bid >> 3);
  int r0 = 2 * j;
  const T* row0 = in + (size_t)((r0 + 0) & (nin - 1)) * nin;
  const T* row1 = in + (size_t)((r0 + 1) & (nin - 1)) * nin;
  const T* row2 = in + (size_t)((r0 + 2) & (nin - 1)) * nin;
  const T* row3 = in + (size_t)((r0 + 3) & (nin - 1)) * nin;
  int t = threadIdx.x;
  int k0 = t * KCNT;
  int c0 = 2 * k0;
  float F[NF];
  if (c0 + NF <= nin) {
    float f[NF];
    load_f<NF>(row0, c0, F);
    load_f<NF>(row1, c0, f);
    #pragma unroll
    for (int u = 0; u < NF; ++u) F[u] += f[u];
    load_f<NF>(row2, c0, f);
    #pragma unroll
    for (int u = 0; u < NF; ++u) F[u] += f[u];
    load_f<NF>(row3, c0, f);
    #pragma unroll
    for (int u = 0; u < NF; ++u) F[u] += f[u];
  } else {
    #pragma unroll
    for (int u = 0; u < NF; ++u) {
      int c = (c0 + u) & (nin - 1);
      F[u] = elt(row0, c) + elt(row1, c) + elt(row2, c) + elt(row3, c);
    }
  }
  float pr[KCNT + 1];
  #pragma unroll
  for (int m = 0; m <= KCNT; ++m) pr[m] = F[2 * m] + F[2 * m + 1];
  float racc = 0.f;
  unsigned short hv[KCNT];
  #pragma unroll
  for (int kl = 0; kl < KCNT; ++kl) {
    float s = pr[kl] + pr[kl + 1];
    hv[kl] = f2bf(s);
    racc += s;
    if (k0 + kl == j) diag[j] = s;
  }
  if constexpr (KCNT == 8) {
    short8v o8;
    #pragma unroll
    for (int kl = 0; kl < 8; ++kl) o8[kl] = (short)hv[kl];
    if (outh) *(short8v*)&outh[(size_t)j * n + k0] = o8;
    *(short8v*)&outp[pidx(j, k0, n)] = o8;
  } else {
    uint2 o4;
    o4.x = (unsigned)hv[0] | ((unsigned)hv[1] << 16);
    o4.y = (unsigned)hv[2] | ((unsigned)hv[3] << 16);
    if (outh) *(uint2*)&outh[(size_t)j * n + k0] = o4;
    *(uint2*)&outp[pidx(j, k0, n)] = o4;
  }
  #pragma unroll
  for (int o = 32; o > 0; o >>= 1) racc += __shfl_xor(racc, o);
  if ((threadIdx.x & 63) == 0) red[threadIdx.x >> 6] = racc;
  __syncthreads();
  if (threadIdx.x == 0) rs[j] = red[0] + red[1] + red[2] + red[3];
}

// ---- K hi/lo + V packed from x (flat, 4 elements/thread)
static __device__ void split_body(const float* __restrict__ X,
                                  unsigned short* __restrict__ Kph,
                                  unsigned short* __restrict__ Kpl,
                                  unsigned short* __restrict__ Vp,
                                  int bb) {
  #pragma unroll
  for (int r = 0; r < 4; ++r) {
    int e = bb * 1024 + r * 256 + threadIdx.x;
    int i = e >> 7, d = e & 127;
    float v = X[e];
    unsigned short hi = f2bf(v);
    Kph[pidx(i, d, 128)] = hi;                    // K consumed r=node, c=feature
    Kpl[pidx(i, d, 128)] = f2bf(v - bf2f(hi));
    Vp[pidx(d, i, 4096)] = hi;                    // V consumed r=feature, c=node
  }
}

// ---- 16x128 @ 128x128 gemm body (xs in LDS, thread owns col d)
static __device__ __forceinline__ void gemm16x128(const float (*xs)[128],
                                                  const float* __restrict__ W,
                                                  int d, float* acc) {
  #pragma unroll
  for (int i = 0; i < 16; ++i) acc[i] = 0.f;
  for (int e = 0; e < 128; e += 4) {
    float w0 = W[(e + 0) * 128 + d];
    float w1 = W[(e + 1) * 128 + d];
    float w2 = W[(e + 2) * 128 + d];
    float w3 = W[(e + 3) * 128 + d];
    #pragma unroll
    for (int i = 0; i < 16; ++i) {
      f32x4 xv = *(const f32x4*)&xs[i][e];
      float a = acc[i];
      a = fmaf(xv[0], w0, a);
      a = fmaf(xv[1], w1, a);
      a = fmaf(xv[2], w2, a);
      a = fmaf(xv[3], w3, a);
      acc[i] = a;
    }
  }
}

// ---- 8-row variant: rows ibase..ibase+7 of xs
static __device__ __forceinline__ void gemm8x128(const float (*xs)[128], int ibase,
                                                 const float* __restrict__ W,
                                                 int d, float* acc) {
  #pragma unroll
  for (int i = 0; i < 8; ++i) acc[i] = 0.f;
  for (int e = 0; e < 128; e += 4) {
    float w0 = W[(e + 0) * 128 + d];
    float w1 = W[(e + 1) * 128 + d];
    float w2 = W[(e + 2) * 128 + d];
    float w3 = W[(e + 3) * 128 + d];
    #pragma unroll
    for (int i = 0; i < 8; ++i) {
      f32x4 xv = *(const f32x4*)&xs[ibase + i][e];
      float a = acc[i];
      a = fmaf(xv[0], w0, a);
      a = fmaf(xv[1], w1, a);
      a = fmaf(xv[2], w2, a);
      a = fmaf(xv[3], w3, a);
      acc[i] = a;
    }
  }
}

// ---- x1b = row-pool(x); Q = x1b @ ca1 -> packed hi/lo. 128 threads per tile.
static __device__ void gemm_q_body(const float* __restrict__ x,
                                   const float* __restrict__ W,
                                   float* __restrict__ x1b,
                                   unsigned short* __restrict__ Qph,
                                   unsigned short* __restrict__ Qpl,
                                   int tile, float (*xs)[128], int d) {
  int r0 = tile * 16;
  #pragma unroll
  for (int i = 0; i < 16; ++i) {
    int rr = 2 * (r0 + i);
    float v = x[(size_t)((rr + 0) & 4095) * 128 + d] + x[(size_t)((rr + 1) & 4095) * 128 + d] +
              x[(size_t)((rr + 2) & 4095) * 128 + d] + x[(size_t)((rr + 3) & 4095) * 128 + d];
    xs[i][d] = v;
    x1b[(size_t)(r0 + i) * 128 + d] = v;
  }
  __syncthreads();
  float acc[16];
  gemm16x128(xs, W, d, acc);
  #pragma unroll
  for (int i = 0; i < 16; ++i) {
    size_t o = pidx(r0 + i, d, 128);              // Q consumed r=node, c=feature
    unsigned short hi = f2bf(acc[i]);
    Qph[o] = hi;
    Qpl[o] = f2bf(acc[i] - bf2f(hi));
  }
}

// ---- mega1: K/V split || gemm_q || pool_adj(level1)   (R9 structure)
__global__ __launch_bounds__(256) void mega1_kernel(const float* __restrict__ newadj,
                                                    unsigned short* __restrict__ adj1h,
                                                    unsigned short* __restrict__ adj1p,
                                                    float* __restrict__ rs1,
                                                    float* __restrict__ diag1,
                                                    const float* __restrict__ x,
                                                    unsigned short* __restrict__ Kph,
                                                    unsigned short* __restrict__ Kpl,
                                                    unsigned short* __restrict__ Vp,
                                                    const float* __restrict__ ca1,
                                                    float* __restrict__ x1b,
                                                    unsigned short* __restrict__ Qph,
                                                    unsigned short* __restrict__ Qpl) {
  __shared__ __align__(16) char smem[16384];
  int b = blockIdx.x;
  if (b < 512) {
    split_body(x, Kph, Kpl, Vp, b);
  } else if (b < 576) {
    int half = threadIdx.x >> 7, d = threadIdx.x & 127;
    float (*xs)[128] = (float (*)[128])(smem + half * 8192);
    gemm_q_body(x, ca1, x1b, Qph, Qpl, (b - 512) * 2 + half, xs, d);
  } else {
    pool_adj_body<float, 8>(newadj, adj1h, adj1p, rs1, diag1, 2048, 4096, b - 576, (float*)smem);
  }
}

// ---- split-K flash attention (standalone, R9 structure).
// 512 blocks x 4 waves; waves share kc -> identical K/V fragment loads hit L1.
__global__ __launch_bounds__(256) void flash_kernel(const short8v* __restrict__ Qh8,
                                                    const short8v* __restrict__ Ql8,
                                                    const short8v* __restrict__ Kh8,
                                                    const short8v* __restrict__ Kl8,
                                                    const short8v* __restrict__ V8,
                                                    uint2* __restrict__ pacc2,
                                                    float* __restrict__ pm,
                                                    float* __restrict__ pl) {
  __shared__ unsigned short Pbuf[4][16][32];
  int w = threadIdx.x >> 6, lane = threadIdx.x & 63;
  int kc = blockIdx.x & 15;
  int jt = (blockIdx.x >> 4) * 4 + w;
  unsigned short (*P)[32] = Pbuf[w];
  int q = lane & 15, g = lane >> 4;
  int j = jt * 16 + q;
  int kbase = kc * 256;
  int twoj = 2 * j;

  short8v qh[4], ql[4];
  #pragma unroll
  for (int c = 0; c < 4; ++c) {
    qh[c] = Qh8[(size_t)(jt * 4 + c) * 64 + lane];
    ql[c] = Ql8[(size_t)(jt * 4 + c) * 64 + lane];
  }
  float m = -1e30f, l = 0.f;
  f32x4 acc[8];
  #pragma unroll
  for (int t = 0; t < 8; ++t) acc[t] = (f32x4){0.f, 0.f, 0.f, 0.f};

  for (int step = 0; step < 8; ++step) {
    int kt = kbase + step * 32;
    size_t fa = (size_t)(kt >> 4) * 4;        // rowblock a (even), b = a+1
    f32x4 z = {0.f, 0.f, 0.f, 0.f};
    f32x4 hh0 = z, hl0 = z, lh0 = z, hh1 = z, hl1 = z, lh1 = z;
    __builtin_amdgcn_s_setprio(1);
    #pragma unroll
    for (int c = 0; c < 4; ++c) {
      short8v ah = Kh8[(fa + c) * 64 + lane];
      short8v al = Kl8[(fa + c) * 64 + lane];
      short8v bh = Kh8[(fa + 4 + c) * 64 + lane];
      short8v bl = Kl8[(fa + 4 + c) * 64 + lane];
      hh0 = mfma16(ah, qh[c], hh0);   // 6 independent 4-deep chains
      hh1 = mfma16(bh, qh[c], hh1);
      hl0 = mfma16(ah, ql[c], hl0);
      hl1 = mfma16(bh, ql[c], hl1);
      lh0 = mfma16(al, qh[c], lh0);
      lh1 = mfma16(bl, qh[c], lh1);
    }
    __builtin_amdgcn_s_setprio(0);
    // prefetch V fragments (contiguous packed): consumed after softmax
    short8v vfrag[8];
    #pragma unroll
    for (int t = 0; t < 8; ++t)
      vfrag[t] = V8[((size_t)t * 128 + (kt >> 5)) * 64 + lane];

    f32x4 s0 = hh0 + hl0 + lh0;
    f32x4 s1 = hh1 + hl1 + lh1;
    float sv[8];
    #pragma unroll
    for (int r = 0; r < 4; ++r) {
      int k0 = kt + g * 4 + r;          // D row = k-within-tile = 4g+r
      float v0 = s0[r];
      if (((k0 - twoj) & 4095) < 4) v0 = 0.f;
      sv[r] = v0;
      int k1 = k0 + 16;
      float v1 = s1[r];
      if (((k1 - twoj) & 4095) < 4) v1 = 0.f;
      sv[4 + r] = v1;
    }
    float cmx = sv[0];
    #pragma unroll
    for (int r = 1; r < 8; ++r) cmx = fmaxf(cmx, sv[r]);
    cmx = fmaxf(cmx, __shfl_xor(cmx, 16));
    cmx = fmaxf(cmx, __shfl_xor(cmx, 32));
    float mnew = fmaxf(m, cmx);
    float ps = 0.f;
    unsigned short pb[8];
    #pragma unroll
    for (int r = 0; r < 8; ++r) {
      float pv = __expf(sv[r] - mnew);
      ps += pv;
      pb[r] = f2bf(pv);
    }
    ps += __shfl_xor(ps, 16);
    ps += __shfl_xor(ps, 32);
    if (__any(cmx > m)) {               // defer-rescale: skip when max didn't grow
      float scl = __expf(m - mnew);
      l *= scl;
      float sc0 = __shfl(scl, 4 * g + 0);
      float sc1 = __shfl(scl, 4 * g + 1);
      float sc2 = __shfl(scl, 4 * g + 2);
      float sc3 = __shfl(scl, 4 * g + 3);
      #pragma unroll
      for (int t = 0; t < 8; ++t) {
        acc[t][0] *= sc0; acc[t][1] *= sc1; acc[t][2] *= sc2; acc[t][3] *= sc3;
      }
    }
    m = mnew;
    l += ps;
    // write P[q][k_local]: tile a k_local=4g+r, tile b 16+4g+r (packed pairs)
    *(unsigned*)&P[q][4 * g]          = (unsigned)pb[0] | ((unsigned)pb[1] << 16);
    *(unsigned*)&P[q][4 * g + 2]      = (unsigned)pb[2] | ((unsigned)pb[3] << 16);
    *(unsigned*)&P[q][16 + 4 * g]     = (unsigned)pb[4] | ((unsigned)pb[5] << 16);
    *(unsigned*)&P[q][16 + 4 * g + 2] = (unsigned)pb[6] | ((unsigned)pb[7] << 16);
    __syncthreads();
    short8v pa = *(const short8v*)&P[q][8 * g];   // A-frag: row q, k=8g+e
    __builtin_amdgcn_s_setprio(1);
    #pragma unroll
    for (int t = 0; t < 8; ++t) acc[t] = mfma16(pa, vfrag[t], acc[t]);
    __builtin_amdgcn_s_setprio(0);
    __syncthreads();
  }
  size_t tau = (size_t)jt * 16 + kc;
  #pragma unroll
  for (int t = 0; t < 8; ++t) {
    uint2 o;
    o.x = (unsigned)f2bf(acc[t][0]) | ((unsigned)f2bf(acc[t][1]) << 16);
    o.y = (unsigned)f2bf(acc[t][2]) | ((unsigned)f2bf(acc[t][3]) << 16);
    pacc2[(tau * 8 + t) * 64 + lane] = o;
  }
  if (g == 0) {
    pm[(size_t)j * 16 + kc] = m;
    pl[(size_t)j * 16 + kc] = l;
  }
}

// ---- merge split-K partials (LDS-staged, coalesced) -> x1; y = d1.*(x1@W1); packed yT
// One jt (16 rows) per block; its ENTIRE pacc input is 64KB contiguous.
__global__ __launch_bounds__(256) void combine_gemm_kernel(const uint4* __restrict__ pacc4,
                                                           const float* __restrict__ pm,
                                                           const float* __restrict__ pl,
                                                           const float* __restrict__ x1b,
                                                           const float* __restrict__ W,
                                                           const float* __restrict__ rs,
                                                           const float* __restrict__ diag,
                                                           float* __restrict__ yB,
                                                           unsigned short* __restrict__ ypack,
                                                           int M) {
  __shared__ unsigned short pL[32768];      // 64 KB: [kc*2048 + t*256 + (g*16+q)*4 + r]
  __shared__ float pmL[256], plL[256];
  __shared__ float xs[16][128];
  int jt = blockIdx.x;
  int r0 = jt * 16;
  int tid = threadIdx.x;
  const uint4* src = pacc4 + (size_t)jt * 4096;   // 16kc*8t*64lane uint2 = 4096 uint4
  uint4* dst = (uint4*)pL;
  #pragma unroll
  for (int u = 0; u < 16; ++u) dst[u * 256 + tid] = src[u * 256 + tid];
  pmL[tid] = pm[(size_t)r0 * 16 + tid];
  plL[tid] = pl[(size_t)r0 * 16 + tid];
  __syncthreads();
  int h = tid >> 7, d = tid & 127;
  int t = d >> 4, q = d & 15;
  #pragma unroll
  for (int ii = 0; ii < 8; ++ii) {
    int i = h * 8 + ii;
    int j = r0 + i;
    int g = i >> 2, r = i & 3;
    int off = t * 256 + (g * 16 + q) * 4 + r;
    float Mx = -1e30f;
    #pragma unroll
    for (int c = 0; c < 16; ++c) Mx = fmaxf(Mx, pmL[i * 16 + c]);
    float L = 0.f, o = 0.f;
    #pragma unroll
    for (int c = 0; c < 16; ++c) {
      float w = __expf(pmL[i * 16 + c] - Mx);
      L += plL[i * 16 + c] * w;
      o += w * bf2f(pL[c * 2048 + off]);
    }
    xs[i][d] = o / L + x1b[(size_t)j * 128 + d];
  }
  __syncthreads();
  float acc[8];
  gemm8x128(xs, h * 8, W, d, acc);
  short8v t0;
  #pragma unroll
  for (int ii = 0; ii < 8; ++ii) {
    int j = r0 + h * 8 + ii;
    float dv = rsqrtf(fmaxf(rs[j] - diag[j] + 1.f, 1.f));
    float v = acc[ii] * dv;
    yB[(size_t)j * 128 + d] = v;
    t0[ii] = (short)f2bf(v);
  }
  // y consumed as B-operand: r = feature d, c = node j
  *(short8v*)&ypack[pidx(d, r0 + h * 8, M)] = t0;
}

// ---- one-wave MFMA tile on packed operands: C_ks partial = A @ B
static __device__ void mfma_tile_body(const short8v* __restrict__ A8,
                                      const short8v* __restrict__ B8,
                                      float* __restrict__ C, int K32, int M,
                                      int jt, int nt, int ks, int lane) {
  int q = lane & 15, g = lane >> 4;
  int half = K32 >> 1;
  const short8v* ap = A8 + ((size_t)jt * K32 + ks * half) * 64 + lane;
  const short8v* bp = B8 + ((size_t)nt * K32 + ks * half) * 64 + lane;
  f32x4 acc = {0.f, 0.f, 0.f, 0.f};
  for (int kc = 0; kc < half; kc += 4) {
    #pragma unroll
    for (int u = 0; u < 4; ++u)
      acc = mfma16(ap[(size_t)(kc + u) * 64], bp[(size_t)(kc + u) * 64], acc);
  }
  float* Cp = C + (size_t)ks * M * 128;
  #pragma unroll
  for (int r = 0; r < 4; ++r)
    Cp[(size_t)(jt * 16 + g * 4 + r) * 128 + nt * 16 + q] = acc[r];
}

// ---- mega2: mfma_gemm(level1, 4 waves/block) || pool_adj(level2, packed-only)
//      Block 0 also zeroes the completion counter for epi_final.
__global__ __launch_bounds__(256) void mega2_kernel(const unsigned short* __restrict__ adj1h,
                                                    const short8v* __restrict__ adj1p8,
                                                    const short8v* __restrict__ yp8,
                                                    float* __restrict__ G,
                                                    unsigned short* __restrict__ adj2p,
                                                    float* __restrict__ rs2,
                                                    float* __restrict__ diag2,
                                                    unsigned* __restrict__ cnt) {
  __shared__ float red[4];
  int b = blockIdx.x;
  if (b == 0 && threadIdx.x == 0) *cnt = 0;
  if (b < 512) {
    int fid = b * 4 + (threadIdx.x >> 6);       // [0,2048)
    int jt = fid & 127, nt = (fid >> 7) & 7, ks = fid >> 10;
    mfma_tile_body(adj1p8, yp8, G, 64, 2048, jt, nt, ks, threadIdx.x & 63);
  } else {
    pool_adj_body<unsigned short, 4>(adj1h, nullptr, adj2p, rs2, diag2, 1024, 2048, b - 512, red);
  }
}

// ---- GCN epilogue element: h[r][d] (G = 2 K-split partials, n rows each)
static __device__ __forceinline__ float epi_h(const float* __restrict__ G,
                                              const float* __restrict__ y,
                                              const float* __restrict__ rs,
                                              const float* __restrict__ diag,
                                              const float* __restrict__ bias,
                                              int n, int r, int d, bool relu) {
  float dv = rsqrtf(fmaxf(rs[r] - diag[r] + 1.f, 1.f));
  float gs = G[(size_t)r * 128 + d] + G[(size_t)(n + r) * 128 + d];
  float v = dv * (gs + (1.f - diag[r]) * y[(size_t)r * 128 + d]) + bias[d];
  return relu ? fmaxf(v, 0.f) : v;
}

// ---- epi_final: level-2 collapsed algebraically.
// colsum(h2, real rows, no bias) = sum_k u[k]*y2[k,:], u[k] = w[k] + d2[k](1-diag2[k]),
// w[k] = sum_j d2[j]*adj2[j,k]. Block b owns k-range [8b..8b+7]: it computes
// w (coalesced chunks of packed adj2), its y2 rows IN REGISTERS
// (x2 = pool(relu-gcn1); y2 = d2.*(x2@W2)), the u-weighted partial, and the
// gated last block finishes mean + linear + relu + log_softmax.
__global__ __launch_bounds__(128) void epi_final_kernel(const float* __restrict__ G,
                                                        const float* __restrict__ yB,
                                                        const float* __restrict__ rs1,
                                                        const float* __restrict__ diag1,
                                                        const float* __restrict__ b1,
                                                        const float* __restrict__ W,
                                                        const float* __restrict__ rs2,
                                                        const float* __restrict__ diag2,
                                                        const float* __restrict__ b2,
                                                        const unsigned short* __restrict__ adj2p,
                                                        float* __restrict__ part,
                                                        unsigned* __restrict__ cnt,
                                                        const float* __restrict__ Wlin,
                                                        const float* __restrict__ blin,
                                                        float* __restrict__ out,
                                                        int n1) {
  __shared__ float xs[8][128];
  __shared__ float wred[16][8];
  __shared__ float uval[8];
  __shared__ float rr0[128], rr1[128];
  __shared__ unsigned doneS;
  int b = blockIdx.x;            // 0..127, k-range = rows r0..r0+7
  int tid = threadIdx.x;
  int r0 = b * 8;
  // ---- w[r0+u] = sum_r d2[r] * adj2[r, r0+u]; packed chunk walk, coalesced
  {
    const unsigned short* base = adj2p + (size_t)(b >> 2) * 512 + (size_t)(b & 3) * 128 + tid;
    int s = tid >> 3;                           // r within 16-row group
    float wacc = 0.f;
    for (int mm = 0; mm < 64; ++mm) {
      int r = mm * 16 + s;
      float d2r = rsqrtf(fmaxf(rs2[r] - diag2[r] + 1.f, 1.f));
      wacc += d2r * bf2f(base[(size_t)mm * 16384]);
    }
    wred[s][tid & 7] = wacc;
  }
  __syncthreads();
  if (tid < 8) {
    float wsum = 0.f;
    #pragma unroll
    for (int s2 = 0; s2 < 16; ++s2) wsum += wred[s2][tid];
    int k = r0 + tid;
    float d2k = rsqrtf(fmaxf(rs2[k] - diag2[k] + 1.f, 1.f));
    uval[tid] = wsum + d2k * (1.f - diag2[k]);
  }
  // ---- x2 rows r0..r0+7 (pool of relu-gcn1), y2 in registers, u-weighted partial
  int d = tid;
  #pragma unroll
  for (int i = 0; i < 8; ++i) {
    int rr = 2 * (r0 + i);
    float s = 0.f;
    #pragma unroll
    for (int a = 0; a < 4; ++a)
      s += epi_h(G, yB, rs1, diag1, b1, n1, (rr + a) & (n1 - 1), d, true);
    xs[i][d] = s;
  }
  __syncthreads();                              // also publishes uval
  float acc[8];
  gemm8x128(xs, 0, W, d, acc);
  float pd = 0.f;
  #pragma unroll
  for (int i = 0; i < 8; ++i) {
    int j = r0 + i;
    float dv = rsqrtf(fmaxf(rs2[j] - diag2[j] + 1.f, 1.f));
    pd += uval[i] * (acc[i] * dv);
  }
  part[(size_t)b * 128 + d] = pd;
  __threadfence();
  __syncthreads();
  if (tid == 0) doneS = atomicAdd(cnt, 1u);
  __syncthreads();
  if (doneS == 127) {                           // last block: all partials visible
    __threadfence();
    float cs = 0.f;
    for (int bb = 0; bb < 128; ++bb) cs += part[(size_t)bb * 128 + d];
    // + 1024*b2 (real rows' bias) + 1024*b2 (phantom rows) -> /2048 = + b2
    float mean = cs * (1.f / 2048.f) + b2[d];
    rr0[d] = mean * Wlin[d];
    rr1[d] = mean * Wlin[128 + d];
    __syncthreads();
    for (int sred = 64; sred > 0; sred >>= 1) {
      if (tid < sred) { rr0[tid] += rr0[tid + sred]; rr1[tid] += rr1[tid + sred]; }
      __syncthreads();
    }
    if (tid == 0) {
      float z0 = fmaxf(rr0[0] + blin[0], 0.f);
      float z1 = fmaxf(rr1[0] + blin[1], 0.f);
      float mz = fmaxf(z0, z1);
      float lse = mz + logf(__expf(z0 - mz) + __expf(z1 - mz));
      out[0] = z0 - lse;
      out[1] = z1 - lse;
    }
  }
}

extern "C" void kernel_launch(void* const* d_in, const int* in_sizes, int n_in,
                              void* d_out, int out_size, void* d_ws, size_t ws_size,
                              hipStream_t stream) {
  const float* x      = (const float*)d_in[0];
  const float* eidx   = (const float*)d_in[1];
  const float* newadj = eidx + (size_t)4096 * 4096;  // edge_index[1]
  const float* ca1    = (const float*)d_in[3];
  const float* W1     = (const float*)d_in[4];
  const float* b1     = (const float*)d_in[5];
  const float* W2     = (const float*)d_in[6];
  const float* b2     = (const float*)d_in[7];
  const float* Wlin   = (const float*)d_in[8];
  const float* blin   = (const float*)d_in[9];
  float* out = (float*)d_out;

  if (ws_size < 42u * 1024u * 1024u) return;

  char* p = (char*)d_ws;
  auto alloc = [&](size_t bytes) -> char* {
    char* r = p; p += (bytes + 255) & ~(size_t)255; return r;
  };
  unsigned short* adj1h = (unsigned short*)alloc((size_t)2048 * 2048 * 2);  // row-major (lvl2 pool input)
  unsigned short* adj1p = (unsigned short*)alloc((size_t)2048 * 2048 * 2);  // packed (MFMA A)
  float* d1raw = (float*)alloc(2048 * 4);
  float* diag1 = (float*)alloc(2048 * 4);
  float* x1b   = (float*)alloc((size_t)2048 * 128 * 4);
  unsigned short* Qph = (unsigned short*)alloc((size_t)2048 * 128 * 2);
  unsigned short* Qpl = (unsigned short*)alloc((size_t)2048 * 128 * 2);
  unsigned short* Kph = (unsigned short*)alloc((size_t)4096 * 128 * 2);
  unsigned short* Kpl = (unsigned short*)alloc((size_t)4096 * 128 * 2);
  unsigned short* Vp  = (unsigned short*)alloc((size_t)4096 * 128 * 2);
  float* pmB   = (float*)alloc((size_t)2048 * 16 * 4);
  float* plB   = (float*)alloc((size_t)2048 * 16 * 4);
  uint2* pacc2 = (uint2*)alloc((size_t)2048 * 8 * 64 * 8);
  float* yB    = (float*)alloc((size_t)2048 * 128 * 4);
  unsigned short* ypack = (unsigned short*)alloc((size_t)2048 * 128 * 2);
  float* G     = (float*)alloc((size_t)2 * 2048 * 128 * 4);
  unsigned short* adj2p = (unsigned short*)alloc((size_t)1024 * 1024 * 2);
  float* d2raw = (float*)alloc(1024 * 4);
  float* diag2 = (float*)alloc(1024 * 4);
  float* part  = (float*)alloc((size_t)128 * 128 * 4);
  unsigned* cnt = (unsigned*)alloc(256);

  // 1. K/V packed split || x1b + Q packed gemm || pool_adj1 (row-major+packed)
  mega1_kernel<<<2624, 256, 0, stream>>>(newadj, adj1h, adj1p, d1raw, diag1,
                                         x, Kph, Kpl, Vp, ca1, x1b, Qph, Qpl);
  // 2. flash attention partials (4 lockstep waves share K/V per block)
  flash_kernel<<<512, 256, 0, stream>>>((const short8v*)Qph, (const short8v*)Qpl,
                                        (const short8v*)Kph, (const short8v*)Kpl,
                                        (const short8v*)Vp, pacc2, pmB, plB);
  // 3. combine (LDS-staged coalesced) -> x1; y = d1 .* (x1 @ W1); packed yT
  combine_gemm_kernel<<<128, 256, 0, stream>>>((const uint4*)pacc2, pmB, plB,
                                               x1b, W1, d1raw, diag1, yB, ypack, 2048);
  // 4. G (2 partials) = adj1 @ y (packed) || pool_adj2 (packed); zero cnt
  mega2_kernel<<<1536, 256, 0, stream>>>(adj1h, (const short8v*)adj1p, (const short8v*)ypack,
                                         G, adj2p, d2raw, diag2, cnt);
  // 5. epi_final: w from packed adj2, y2 in registers, u-weighted colsum,
  //    gated last block -> mean + linear + relu + log_softmax
  epi_final_kernel<<<128, 128, 0, stream>>>(G, yB, d1raw, diag1, b1, W2,
                                            d2raw, diag2, b2, adj2p,
                                            part, cnt, Wlin, blin, out, 2048);
}